// Round 6
// baseline (769.211 us; speedup 1.0000x reference)
//
#include <hip/hip_runtime.h>
#include <hip/hip_bf16.h>
#include <math.h>

// DeepSeekMoE: T=4096, H=1024, F=4096, E=8, top-2 sigmoid routing.
// Round 6: faithful m201-style 8-phase 256^2/BK=64 grouped GEMM for BOTH GEMMs
// (counted vmcnt(6) @ ph4/ph8, 3 half-tiles in flight, T2 chunk-swizzle,
// setprio). Separate weight-convert pass restored (round-5 fusion regressed).

#define T_TOK 4096
#define H_DIM 1024
#define F_DIM 4096
#define NEXP  8
#define RT    (2 * T_TOK)
#define RPAD  512

typedef __bf16 bf16_t;
typedef __bf16 bf16x8 __attribute__((ext_vector_type(8)));
typedef float  f32x4  __attribute__((ext_vector_type(4)));
typedef unsigned short u16x8 __attribute__((ext_vector_type(8)));

#define CFENCE() asm volatile("" ::: "memory")
#define BAR()    do { CFENCE(); __builtin_amdgcn_s_barrier(); CFENCE(); } while (0)
#define LGKM0()  asm volatile("s_waitcnt lgkmcnt(0)" ::: "memory")
#define VM6()    asm volatile("s_waitcnt vmcnt(6)" ::: "memory")
#define VM0()    asm volatile("s_waitcnt vmcnt(0)" ::: "memory")

__device__ __forceinline__ unsigned short f2bf(float f) {
  union { bf16_t b; unsigned short u; } cv;
  cv.b = (bf16_t)f;
  return cv.u;
}

__device__ __forceinline__ float gelu_exact(float v) {
  return 0.5f * v * (1.0f + erff(v * 0.70710678118654752f));
}

// bijective XCD swizzle (m204)
__device__ __forceinline__ int xcd_swizzle(int orig, int nwg) {
  const int q = nwg >> 3, r = nwg & 7;
  const int xcd = orig & 7, idx = orig >> 3;
  return (xcd < r ? xcd * (q + 1) : r * (q + 1) + (xcd - r) * q) + idx;
}

// ---------------------------------------------------------------- small kernels

__global__ void zero_kernel(int* p) {
  if (threadIdx.x < 16) p[threadIdx.x] = 0;
}

// all four weight tensors -> contiguous bf16 dst (w1s|w2s|w1e|w2e)
__global__ void convert4_kernel(const float* __restrict__ s0, const float* __restrict__ s1,
                                const float* __restrict__ s2, const float* __restrict__ s3,
                                unsigned short* __restrict__ dst) {
  const long N0 = (long)F_DIM * H_DIM / 8;
  const long N1 = N0 + (long)H_DIM * F_DIM / 8;
  const long N2 = N1 + (long)NEXP * F_DIM * H_DIM / 8;
  const long NT = N2 + (long)NEXP * H_DIM * F_DIM / 8;
  long i = (long)blockIdx.x * blockDim.x + threadIdx.x;
  const long stride = (long)gridDim.x * blockDim.x;
  for (; i < NT; i += stride) {
    const float* s; long j;
    if (i < N0)      { s = s0; j = i; }
    else if (i < N1) { s = s1; j = i - N0; }
    else if (i < N2) { s = s2; j = i - N1; }
    else             { s = s3; j = i - N2; }
    const f32x4* sp = (const f32x4*)s + j * 2;
    f32x4 v0 = sp[0], v1 = sp[1];
    u16x8 o;
    #pragma unroll
    for (int k = 0; k < 4; ++k) { o[k] = f2bf(v0[k]); o[4 + k] = f2bf(v1[k]); }
    *(u16x8*)(dst + i * 8) = o;
  }
}

// one wave per token: 8 gate scores -> sigmoid -> top2; also emits x in bf16
__global__ void gate_kernel(const float* __restrict__ x, const float* __restrict__ gw,
                            const float* __restrict__ gb, const float* __restrict__ rb,
                            unsigned short* __restrict__ x_bf,
                            int* __restrict__ tok_e, float* __restrict__ tok_w,
                            int* __restrict__ counts) {
  int tkn = blockIdx.x;
  int lane = threadIdx.x;
  float acc[NEXP];
  #pragma unroll
  for (int e = 0; e < NEXP; ++e) acc[e] = 0.f;
  const float* xr = x + (long)tkn * H_DIM;
  unsigned short* xbr = x_bf + (long)tkn * H_DIM;
  for (int k = lane; k < H_DIM; k += 64) {
    float xv = xr[k];
    xbr[k] = f2bf(xv);
    #pragma unroll
    for (int e = 0; e < NEXP; ++e) acc[e] += xv * gw[e * H_DIM + k];
  }
  #pragma unroll
  for (int off = 32; off > 0; off >>= 1) {
    #pragma unroll
    for (int e = 0; e < NEXP; ++e) acc[e] += __shfl_xor(acc[e], off, 64);
  }
  if (lane == 0) {
    float s[NEXP];
    #pragma unroll
    for (int e = 0; e < NEXP; ++e)
      s[e] = 1.f / (1.f + expf(-(acc[e] + gb[e] + rb[e])));
    int e0 = 0;
    #pragma unroll
    for (int e = 1; e < NEXP; ++e) if (s[e] > s[e0]) e0 = e;
    int e1 = (e0 == 0) ? 1 : 0;
    #pragma unroll
    for (int e = 0; e < NEXP; ++e) if (e != e0 && e != e1 && s[e] > s[e1]) e1 = e;
    tok_e[2 * tkn] = e0;  tok_e[2 * tkn + 1] = e1;
    tok_w[2 * tkn] = s[e0]; tok_w[2 * tkn + 1] = s[e1];
    atomicAdd(&counts[e0], 1);
    atomicAdd(&counts[e1], 1);
  }
}

__global__ void scan_kernel(const int* __restrict__ counts, int* __restrict__ offs) {
  if (threadIdx.x == 0) {
    int o = 0;
    for (int e = 0; e < NEXP; ++e) { offs[e] = o; o += counts[e]; }
  }
}

__global__ void build_kernel(const int* __restrict__ tok_e, const float* __restrict__ tok_w,
                             const int* __restrict__ offs, int* __restrict__ cursor,
                             int* __restrict__ btok, float* __restrict__ bw,
                             int* __restrict__ tokpos) {
  int tkn = blockIdx.x * blockDim.x + threadIdx.x;
  if (tkn >= T_TOK) return;
  #pragma unroll
  for (int k = 0; k < 2; ++k) {
    int e = tok_e[2 * tkn + k];
    int p = offs[e] + atomicAdd(&cursor[e], 1);
    btok[p] = tkn;
    bw[p] = tok_w[2 * tkn + k];
    tokpos[2 * tkn + k] = p;
  }
}

__global__ void gather_kernel(const float* __restrict__ x, const int* __restrict__ btok,
                              unsigned short* __restrict__ gx) {
  int p = blockIdx.x, tid = threadIdx.x;
  int tkn = btok[p];
  const f32x4* s = (const f32x4*)(x + (long)tkn * H_DIM);
  f32x4 v0 = s[tid * 2], v1 = s[tid * 2 + 1];
  u16x8 o;
  #pragma unroll
  for (int j = 0; j < 4; ++j) { o[j] = f2bf(v0[j]); o[4 + j] = f2bf(v1[j]); }
  *(u16x8*)(gx + (long)p * H_DIM + tid * 8) = o;
}

__global__ void combine_kernel(float* __restrict__ out, const float* __restrict__ rout,
                               const int* __restrict__ tokpos) {
  int tkn = blockIdx.x, c = threadIdx.x;
  int p0 = tokpos[2 * tkn], p1 = tokpos[2 * tkn + 1];
  f32x4* o = (f32x4*)out + (long)tkn * 256;
  const f32x4* a = (const f32x4*)rout + (long)p0 * 256;
  const f32x4* b = (const f32x4*)rout + (long)p1 * 256;
  o[c] = o[c] + a[c] + b[c];
}

// ---------------------------------------------------------------- 8-phase grouped GEMM
// C[M,N] = A[M,K] @ B[N,K]^T (+bias). 256x256 tile, BK=64 (2 ks-slices), 8 waves
// (2Mx4N), LDS [2 tilebuf][2 mat][2 ks][256][32] = 128 KB. grid.z: 0..7 experts,
// 8 = shared. MODE 1: gelu->bf16. MODE 2: [*rowscale]->f32.
//
// Iter i reads tiles t=2i (buf0, ph1-4) and t+1 (buf1, ph5-8); one half-tile
// (mat,ks of a tile) staged per phase:
//   ph1:(t+1).A.ks1  ph2:(t+2).B.ks0  ph3:(t+2).A.ks0  ph4:(t+2).B.ks1 +vm6
//   ph5:(t+2).A.ks1  ph6:(t+3).B.ks0  ph7:(t+3).A.ks0  ph8:(t+3).B.ks1 +vm6
// vmcnt(6) keeps the newest 3 half-tiles pending; induction: ph4 gate drains
// all of t+1 (read ph5-8), ph8 gate drains all of t+2 (read next ph1-4).
// Every slot overwrite lands >=1 barrier after that slot's last read.
template<int MODE>
__global__ __launch_bounds__(512, 2)
void gemm8p(const unsigned short* __restrict__ Ash, const unsigned short* __restrict__ Art,
            const unsigned short* __restrict__ Wsh, const unsigned short* __restrict__ Wrt,
            const float* __restrict__ bsh, const float* __restrict__ brt,
            void* __restrict__ Csh, void* __restrict__ Crt,
            const float* __restrict__ bwgt,
            const int* __restrict__ cnts, const int* __restrict__ offs,
            int N, int K) {
  __shared__ __align__(16) unsigned short lds[2][2][2][256][32];   // 128 KB
  const int gxd = gridDim.x;
  const int nwg = gxd * gridDim.y;
  const int wg = xcd_swizzle(blockIdx.y * gxd + blockIdx.x, nwg);
  const int mb = wg % gxd, nb = wg / gxd;
  const int z = blockIdx.z;

  const unsigned short* A;
  const unsigned short* Bp;
  const float* bias;
  const float* rs = nullptr;
  char* Cb;
  int mcnt;
  if (z == NEXP) {
    A = Ash; Bp = Wsh; bias = bsh; Cb = (char*)Csh; mcnt = T_TOK;
  } else {
    const int off = offs[z];
    mcnt = cnts[z];
    A = Art + (long)off * K;
    Bp = Wrt + (long)z * N * K;
    bias = brt + z * N;
    if (MODE == 1) Cb = (char*)Crt + (long)off * N * 2;
    else         { Cb = (char*)Crt + (long)off * N * 4; rs = bwgt + off; }
  }
  if (mb * 256 >= mcnt) return;

  const int t = threadIdx.x;
  const int l = t & 63;
  const int w = t >> 6;                       // 8 waves: 2M x 4N
  const int wr = (w >> 2) * 128, wc = (w & 3) * 64;
  const int lr = l & 15;
  const int xch = (l >> 4) ^ (lr & 3);        // swizzled 16B chunk (lane-const)

  char* ldsc = (char*)&lds[0][0][0][0][0];
  f32x4 acc[8][4] = {};
  const int nit = K >> 7;                     // iters of 2 K-tiles (BK=64)

  // frag byte offsets within a [256][32] slot
  int aOff[8], bOff[4];
  #pragma unroll
  for (int m = 0; m < 8; ++m) aOff[m] = (wr + m * 16 + lr) * 64 + xch * 16;
  #pragma unroll
  for (int n = 0; n < 4; ++n) bOff[n] = (wc + n * 16 + lr) * 64 + xch * 16;

  // stage one half-tile (mat,ks) of K-tile `tile` into buf = tile&1.
  // linear LDS dest (gload_lds requirement) + inverse-swizzled global source.
  auto stage = [&](int mat, int ks, int tile) {
    const unsigned short* G = mat ? Bp : A;
    const int rbase = (mat ? nb : mb) * 256;
    unsigned short* dbase = &lds[tile & 1][mat][ks][0][0];
    #pragma unroll
    for (int i = 0; i < 2; ++i) {
      const int row = i * 128 + (t >> 2);
      const int c2 = (t & 3) ^ ((t >> 2) & 3);   // row&3 == (t>>2)&3
      const unsigned short* g = G + (long)(rbase + row) * K + tile * 64 + ks * 32 + c2 * 8;
      unsigned short* d = dbase + i * 4096 + t * 8;
      __builtin_amdgcn_global_load_lds((const __attribute__((address_space(1))) unsigned int*)g,
                                       (__attribute__((address_space(3))) unsigned int*)d, 16, 0, 0);
    }
  };

  bf16x8 aF[4], bF[4];
  auto ldA = [&](int buf, int ks, int mh) {
    const char* p = ldsc + (((buf * 2 + 0) * 2 + ks) << 14);
    #pragma unroll
    for (int m = 0; m < 4; ++m) aF[m] = *(const bf16x8*)(p + aOff[mh * 4 + m]);
  };
  auto ldB = [&](int buf, int ks) {
    const char* p = ldsc + (((buf * 2 + 1) * 2 + ks) << 14);
    #pragma unroll
    for (int n = 0; n < 4; ++n) bF[n] = *(const bf16x8*)(p + bOff[n]);
  };

#define MM(mh)                                                                   \
  do {                                                                           \
    __builtin_amdgcn_s_setprio(1);                                               \
    _Pragma("unroll")                                                            \
    for (int m_ = 0; m_ < 4; ++m_) {                                             \
      _Pragma("unroll")                                                          \
      for (int n_ = 0; n_ < 4; ++n_)                                             \
        acc[(mh) * 4 + m_][n_] = __builtin_amdgcn_mfma_f32_16x16x32_bf16(        \
            aF[m_], bF[n_], acc[(mh) * 4 + m_][n_], 0, 0, 0);                    \
    }                                                                            \
    __builtin_amdgcn_s_setprio(0);                                               \
  } while (0)

  // prologue: t0 all 4 halves + t1 {B.ks0, A.ks0, B.ks1}; vm6 -> t0 landed.
  stage(0, 0, 0); stage(1, 0, 0); stage(0, 1, 0); stage(1, 1, 0);
  stage(1, 0, 1); stage(0, 0, 1); stage(1, 1, 1);
  VM6();
  BAR();

  for (int i = 0; i < nit - 1; ++i) {
    const int t1 = 2 * i + 1, t2 = 2 * i + 2, t3 = 2 * i + 3;
    // ph1
    ldA(0, 0, 0); ldB(0, 0); stage(0, 1, t1);
    BAR(); LGKM0(); MM(0); BAR();
    // ph2
    ldA(0, 0, 1); stage(1, 0, t2);
    BAR(); LGKM0(); MM(1); BAR();
    // ph3
    ldA(0, 1, 0); ldB(0, 1); stage(0, 0, t2);
    BAR(); LGKM0(); MM(0); BAR();
    // ph4
    ldA(0, 1, 1); stage(1, 1, t2); VM6();
    BAR(); LGKM0(); MM(1); BAR();
    // ph5
    ldA(1, 0, 0); ldB(1, 0); stage(0, 1, t2);
    BAR(); LGKM0(); MM(0); BAR();
    // ph6
    ldA(1, 0, 1); stage(1, 0, t3);
    BAR(); LGKM0(); MM(1); BAR();
    // ph7
    ldA(1, 1, 0); ldB(1, 1); stage(0, 0, t3);
    BAR(); LGKM0(); MM(0); BAR();
    // ph8
    ldA(1, 1, 1); stage(1, 1, t3); VM6();
    BAR(); LGKM0(); MM(1); BAR();
  }

  // peeled last iter: stage only (2*nit-1).A.ks1 at ph1; drain at ph4.
  {
    const int t1 = 2 * nit - 1;
    ldA(0, 0, 0); ldB(0, 0); stage(0, 1, t1);
    BAR(); LGKM0(); MM(0); BAR();
    ldA(0, 0, 1);
    BAR(); LGKM0(); MM(1); BAR();
    ldA(0, 1, 0); ldB(0, 1);
    BAR(); LGKM0(); MM(0); BAR();
    ldA(0, 1, 1); VM0();
    BAR(); LGKM0(); MM(1); BAR();
    ldA(1, 0, 0); ldB(1, 0);
    BAR(); LGKM0(); MM(0); BAR();
    ldA(1, 0, 1);
    BAR(); LGKM0(); MM(1); BAR();
    ldA(1, 1, 0); ldB(1, 1);
    BAR(); LGKM0(); MM(0); BAR();
    ldA(1, 1, 1);
    BAR(); LGKM0(); MM(1); BAR();
  }
#undef MM

  // epilogue: C/D layout col=lane&15, row=(lane>>4)*4+j (m89-verified)
  #pragma unroll
  for (int m = 0; m < 8; ++m) {
    #pragma unroll
    for (int n = 0; n < 4; ++n) {
      const int col = nb * 256 + wc + n * 16 + lr;
      const float bc = bias[col];
      #pragma unroll
      for (int j = 0; j < 4; ++j) {
        const int lrow = mb * 256 + wr + m * 16 + (l >> 4) * 4 + j;
        if (lrow >= mcnt) continue;
        float v = acc[m][n][j] + bc;
        if (MODE == 1) {
          ((unsigned short*)Cb)[(long)lrow * N + col] = f2bf(gelu_exact(v));
        } else {
          if (z != NEXP) v *= rs[lrow];
          ((float*)Cb)[(long)lrow * N + col] = v;
        }
      }
    }
  }
}

// ---------------------------------------------------------------- host

extern "C" void kernel_launch(void* const* d_in, const int* in_sizes, int n_in,
                              void* d_out, int out_size, void* d_ws, size_t ws_size,
                              hipStream_t stream) {
  const float* x   = (const float*)d_in[0];
  const float* gw  = (const float*)d_in[1];
  const float* gb  = (const float*)d_in[2];
  const float* rb  = (const float*)d_in[3];
  const float* sw1 = (const float*)d_in[4];
  const float* sb1 = (const float*)d_in[5];
  const float* sw2 = (const float*)d_in[6];
  const float* sb2 = (const float*)d_in[7];
  const float* ew1 = (const float*)d_in[8];
  const float* eb1 = (const float*)d_in[9];
  const float* ew2 = (const float*)d_in[10];
  const float* eb2 = (const float*)d_in[11];

  char* wsp = (char*)d_ws;
  size_t o = 0;
  auto alloc = [&](size_t b) -> void* {
    void* p = wsp + o;
    o = (o + b + 255) & ~(size_t)255;
    return p;
  };
  unsigned short* x_bf = (unsigned short*)alloc((size_t)T_TOK * H_DIM * 2);
  // w1s|w2s|w1e|w2e contiguous (convert4 writes one flat dst)
  unsigned short* w1s  = (unsigned short*)alloc((size_t)F_DIM * H_DIM * 2);
  unsigned short* w2s  = (unsigned short*)alloc((size_t)H_DIM * F_DIM * 2);
  unsigned short* w1e  = (unsigned short*)alloc((size_t)NEXP * F_DIM * H_DIM * 2);
  unsigned short* w2e  = (unsigned short*)alloc((size_t)NEXP * H_DIM * F_DIM * 2);
  unsigned short* gx   = (unsigned short*)alloc((size_t)(RT + RPAD) * H_DIM * 2);
  unsigned short* hbuf = (unsigned short*)alloc((size_t)(T_TOK + RT + RPAD) * F_DIM * 2);
  float* rout          = (float*)alloc((size_t)RT * H_DIM * 4);
  int*   tok_e  = (int*)alloc(2 * T_TOK * 4);
  float* tok_w  = (float*)alloc(2 * T_TOK * 4);
  int*   tokpos = (int*)alloc(2 * T_TOK * 4);
  int*   btok   = (int*)alloc(RT * 4);
  float* bw     = (float*)alloc(RT * 4);
  int*   meta   = (int*)alloc(1024);
  int* counts = meta, *cursor = meta + 8, *offs = meta + 16;
  (void)ws_size; (void)in_sizes; (void)n_in; (void)out_size;

  float* out = (float*)d_out;

  zero_kernel<<<1, 64, 0, stream>>>(meta);
  convert4_kernel<<<4096, 256, 0, stream>>>(sw1, sw2, ew1, ew2, w1s);
  gate_kernel<<<T_TOK, 64, 0, stream>>>(x, gw, gb, rb, x_bf, tok_e, tok_w, counts);
  scan_kernel<<<1, 1, 0, stream>>>(counts, offs);
  build_kernel<<<T_TOK / 256, 256, 0, stream>>>(tok_e, tok_w, offs, cursor, btok, bw, tokpos);
  gather_kernel<<<RT, 128, 0, stream>>>(x, btok, gx);

  // GEMM1: K=1024, N=4096. grid.x=32 covers worst-case expert skew (8192 rows).
  gemm8p<1><<<dim3(RT / 256, F_DIM / 256, NEXP + 1), 512, 0, stream>>>(
      x_bf, gx, w1s, w1e, sb1, eb1,
      hbuf, hbuf + (size_t)T_TOK * F_DIM, nullptr, counts, offs, F_DIM, H_DIM);

  // GEMM2: K=4096, N=1024.
  gemm8p<2><<<dim3(RT / 256, H_DIM / 256, NEXP + 1), 512, 0, stream>>>(
      hbuf, hbuf + (size_t)T_TOK * F_DIM, w2s, w2e, sb2, eb2,
      out, rout, bw, counts, offs, H_DIM, F_DIM);

  combine_kernel<<<T_TOK, 256, 0, stream>>>(out, rout, tokpos);
}

// Round 7
// 697.298 us; speedup vs baseline: 1.1031x; 1.1031x over previous
//
#include <hip/hip_runtime.h>
#include <hip/hip_bf16.h>
#include <math.h>

// DeepSeekMoE: T=4096, H=1024, F=4096, E=8, top-2 sigmoid routing.
// Round 7: back to r3's proven 2-phase GEMM inner loops (410 TF each; 8-phase
// lane abandoned after 2 null iterations). New: flattened 1-D balanced grids --
// scan builds per-group tile tables, blocks map flat_id->(z,mlocal,nb); kills
// the 3x dispatch waste + real-block clumping seen in r3 (Occupancy 18%).

#define T_TOK 4096
#define H_DIM 1024
#define F_DIM 4096
#define NEXP  8
#define RT    (2 * T_TOK)
#define RPAD  512

// worst-case flat grid sizes (fixed for graph capture)
#define G1_TILES 56    // 16 shared + max 40 expert M-tiles (BM=256)
#define G2_TILES 104   // 32 shared + max 72 expert M-tiles (BM=128)
#define G1_GRID  (G1_TILES * 16)   // NB1 = F/256 = 16
#define G2_GRID  (G2_TILES * 8)    // NB2 = H/128 = 8

typedef __bf16 bf16_t;
typedef __bf16 bf16x8 __attribute__((ext_vector_type(8)));
typedef float  f32x4  __attribute__((ext_vector_type(4)));
typedef unsigned short u16x8 __attribute__((ext_vector_type(8)));

__device__ __forceinline__ unsigned short f2bf(float f) {
  union { bf16_t b; unsigned short u; } cv;
  cv.b = (bf16_t)f;
  return cv.u;
}

__device__ __forceinline__ float gelu_exact(float v) {
  return 0.5f * v * (1.0f + erff(v * 0.70710678118654752f));
}

// bijective XCD swizzle (m204)
__device__ __forceinline__ int xcd_swizzle(int orig, int nwg) {
  const int q = nwg >> 3, r = nwg & 7;
  const int xcd = orig & 7, idx = orig >> 3;
  return (xcd < r ? xcd * (q + 1) : r * (q + 1) + (xcd - r) * q) + idx;
}

// ---------------------------------------------------------------- small kernels

__global__ void zero_kernel(int* p) {
  if (threadIdx.x < 16) p[threadIdx.x] = 0;
}

// all four weight tensors -> contiguous bf16 dst (w1s|w2s|w1e|w2e)
__global__ void convert4_kernel(const float* __restrict__ s0, const float* __restrict__ s1,
                                const float* __restrict__ s2, const float* __restrict__ s3,
                                unsigned short* __restrict__ dst) {
  const long N0 = (long)F_DIM * H_DIM / 8;
  const long N1 = N0 + (long)H_DIM * F_DIM / 8;
  const long N2 = N1 + (long)NEXP * F_DIM * H_DIM / 8;
  const long NT = N2 + (long)NEXP * H_DIM * F_DIM / 8;
  long i = (long)blockIdx.x * blockDim.x + threadIdx.x;
  const long stride = (long)gridDim.x * blockDim.x;
  for (; i < NT; i += stride) {
    const float* s; long j;
    if (i < N0)      { s = s0; j = i; }
    else if (i < N1) { s = s1; j = i - N0; }
    else if (i < N2) { s = s2; j = i - N1; }
    else             { s = s3; j = i - N2; }
    const f32x4* sp = (const f32x4*)s + j * 2;
    f32x4 v0 = sp[0], v1 = sp[1];
    u16x8 o;
    #pragma unroll
    for (int k = 0; k < 4; ++k) { o[k] = f2bf(v0[k]); o[4 + k] = f2bf(v1[k]); }
    *(u16x8*)(dst + i * 8) = o;
  }
}

// one wave per token: 8 gate scores -> sigmoid -> top2; also emits x in bf16
__global__ void gate_kernel(const float* __restrict__ x, const float* __restrict__ gw,
                            const float* __restrict__ gb, const float* __restrict__ rb,
                            unsigned short* __restrict__ x_bf,
                            int* __restrict__ tok_e, float* __restrict__ tok_w,
                            int* __restrict__ counts) {
  int tkn = blockIdx.x;
  int lane = threadIdx.x;
  float acc[NEXP];
  #pragma unroll
  for (int e = 0; e < NEXP; ++e) acc[e] = 0.f;
  const float* xr = x + (long)tkn * H_DIM;
  unsigned short* xbr = x_bf + (long)tkn * H_DIM;
  for (int k = lane; k < H_DIM; k += 64) {
    float xv = xr[k];
    xbr[k] = f2bf(xv);
    #pragma unroll
    for (int e = 0; e < NEXP; ++e) acc[e] += xv * gw[e * H_DIM + k];
  }
  #pragma unroll
  for (int off = 32; off > 0; off >>= 1) {
    #pragma unroll
    for (int e = 0; e < NEXP; ++e) acc[e] += __shfl_xor(acc[e], off, 64);
  }
  if (lane == 0) {
    float s[NEXP];
    #pragma unroll
    for (int e = 0; e < NEXP; ++e)
      s[e] = 1.f / (1.f + expf(-(acc[e] + gb[e] + rb[e])));
    int e0 = 0;
    #pragma unroll
    for (int e = 1; e < NEXP; ++e) if (s[e] > s[e0]) e0 = e;
    int e1 = (e0 == 0) ? 1 : 0;
    #pragma unroll
    for (int e = 0; e < NEXP; ++e) if (e != e0 && e != e1 && s[e] > s[e1]) e1 = e;
    tok_e[2 * tkn] = e0;  tok_e[2 * tkn + 1] = e1;
    tok_w[2 * tkn] = s[e0]; tok_w[2 * tkn + 1] = s[e1];
    atomicAdd(&counts[e0], 1);
    atomicAdd(&counts[e1], 1);
  }
}

// row offsets + per-group M-tile offset tables for both GEMMs.
// group order: z=0..7 experts, z=8 shared; t[9] = total tiles.
__global__ void scan_kernel(const int* __restrict__ counts, int* __restrict__ offs,
                            int* __restrict__ t1, int* __restrict__ t2) {
  if (threadIdx.x == 0) {
    int o = 0, a1 = 0, a2 = 0;
    for (int e = 0; e < NEXP; ++e) {
      offs[e] = o;
      t1[e] = a1; t2[e] = a2;
      a1 += (counts[e] + 255) >> 8;
      a2 += (counts[e] + 127) >> 7;
      o += counts[e];
    }
    t1[8] = a1; t2[8] = a2;
    t1[9] = a1 + (T_TOK >> 8);
    t2[9] = a2 + (T_TOK >> 7);
  }
}

__global__ void build_kernel(const int* __restrict__ tok_e, const float* __restrict__ tok_w,
                             const int* __restrict__ offs, int* __restrict__ cursor,
                             int* __restrict__ btok, float* __restrict__ bw,
                             int* __restrict__ tokpos) {
  int tkn = blockIdx.x * blockDim.x + threadIdx.x;
  if (tkn >= T_TOK) return;
  #pragma unroll
  for (int k = 0; k < 2; ++k) {
    int e = tok_e[2 * tkn + k];
    int p = offs[e] + atomicAdd(&cursor[e], 1);
    btok[p] = tkn;
    bw[p] = tok_w[2 * tkn + k];
    tokpos[2 * tkn + k] = p;
  }
}

__global__ void gather_kernel(const float* __restrict__ x, const int* __restrict__ btok,
                              unsigned short* __restrict__ gx) {
  int p = blockIdx.x, tid = threadIdx.x;
  int tkn = btok[p];
  const f32x4* s = (const f32x4*)(x + (long)tkn * H_DIM);
  f32x4 v0 = s[tid * 2], v1 = s[tid * 2 + 1];
  u16x8 o;
  #pragma unroll
  for (int j = 0; j < 4; ++j) { o[j] = f2bf(v0[j]); o[4 + j] = f2bf(v1[j]); }
  *(u16x8*)(gx + (long)p * H_DIM + tid * 8) = o;
}

__global__ void combine_kernel(float* __restrict__ out, const float* __restrict__ rout,
                               const int* __restrict__ tokpos) {
  int tkn = blockIdx.x, c = threadIdx.x;
  int p0 = tokpos[2 * tkn], p1 = tokpos[2 * tkn + 1];
  f32x4* o = (f32x4*)out + (long)tkn * 256;
  const f32x4* a = (const f32x4*)rout + (long)p0 * 256;
  const f32x4* b = (const f32x4*)rout + (long)p1 * 256;
  o[c] = o[c] + a[c] + b[c];
}

// ---------------------------------------------------------------- grouped GEMM1
// Flat grid over real tiles. 256x256, BK=32, 8 waves, 2-phase (r3-proven).
// C = gelu(A @ B^T + bias) bf16. K=1024, N=4096, NB=16.
__global__ __launch_bounds__(512)
void moe_gemm1(const unsigned short* __restrict__ Ash, const unsigned short* __restrict__ Art,
               const unsigned short* __restrict__ Wsh, const unsigned short* __restrict__ Wrt,
               const float* __restrict__ bsh, const float* __restrict__ brt,
               unsigned short* __restrict__ Csh, unsigned short* __restrict__ Crt,
               const int* __restrict__ cnts, const int* __restrict__ offs,
               const int* __restrict__ tt) {
  __shared__ __align__(16) unsigned short lds[2][2][256][32];   // 64 KB
  const int wid = xcd_swizzle(blockIdx.x, G1_GRID);
  const int mt = wid >> 4, nb = wid & 15;
  if (mt >= tt[9]) return;
  int z = 0;
  while (mt >= tt[z + 1]) ++z;          // groups with 0 tiles skip naturally
  const int mlocal = mt - tt[z];

  const unsigned short* A;
  const unsigned short* Bp;
  const float* bias;
  unsigned short* C;
  int mcnt;
  if (z == NEXP) {
    A = Ash; Bp = Wsh; bias = bsh; C = Csh; mcnt = T_TOK;
  } else {
    const int off = offs[z];
    mcnt = cnts[z];
    A = Art + (long)off * H_DIM;
    Bp = Wrt + (long)z * F_DIM * H_DIM;
    bias = brt + z * F_DIM;
    C = Crt + (long)off * F_DIM;
  }

  const int t = threadIdx.x;
  f32x4 acc[8][4] = {};
  const int nk = H_DIM >> 5;   // 32 K-steps

  auto stage = [&](int kt, int buf) {
    #pragma unroll
    for (int i = 0; i < 2; ++i) {
      const int row = i * 128 + (t >> 2);
      const int ch = (t & 3) * 8;
      const unsigned short* ga = A + (long)(mlocal * 256 + row) * H_DIM + kt * 32 + ch;
      const unsigned short* gb = Bp + (long)(nb * 256 + row) * H_DIM + kt * 32 + ch;
      unsigned short* la = &lds[buf][0][0][0] + i * 4096 + t * 8;
      unsigned short* lb = &lds[buf][1][0][0] + i * 4096 + t * 8;
      __builtin_amdgcn_global_load_lds((const __attribute__((address_space(1))) unsigned int*)ga,
                                       (__attribute__((address_space(3))) unsigned int*)la, 16, 0, 0);
      __builtin_amdgcn_global_load_lds((const __attribute__((address_space(1))) unsigned int*)gb,
                                       (__attribute__((address_space(3))) unsigned int*)lb, 16, 0, 0);
    }
  };

  const int l = t & 63;
  const int w = t >> 6;                       // 8 waves: 2M x 4N
  const int wr = (w >> 2) * 128, wc = (w & 3) * 64;
  const int lr = l & 15, lk = (l >> 4) * 8;

  auto compute = [&](int buf) {
    bf16x8 a[8], b[4];
    #pragma unroll
    for (int m = 0; m < 8; ++m) a[m] = *(const bf16x8*)&lds[buf][0][wr + m * 16 + lr][lk];
    #pragma unroll
    for (int n = 0; n < 4; ++n) b[n] = *(const bf16x8*)&lds[buf][1][wc + n * 16 + lr][lk];
    #pragma unroll
    for (int m = 0; m < 8; ++m)
      #pragma unroll
      for (int n = 0; n < 4; ++n)
        acc[m][n] = __builtin_amdgcn_mfma_f32_16x16x32_bf16(a[m], b[n], acc[m][n], 0, 0, 0);
  };

  stage(0, 0);
  asm volatile("s_waitcnt vmcnt(0)" ::: "memory");
  __syncthreads();
  for (int kt = 0; kt < nk - 1; ++kt) {
    const int cur = kt & 1;
    stage(kt + 1, cur ^ 1);
    compute(cur);
    asm volatile("s_waitcnt vmcnt(0)" ::: "memory");
    __syncthreads();
  }
  compute((nk - 1) & 1);

  // epilogue: C/D layout col=lane&15, row=(lane>>4)*4+j (m89-verified)
  #pragma unroll
  for (int m = 0; m < 8; ++m) {
    #pragma unroll
    for (int n = 0; n < 4; ++n) {
      const int col = nb * 256 + wc + n * 16 + lr;
      const float bc = bias[col];
      #pragma unroll
      for (int j = 0; j < 4; ++j) {
        const int lrow = mlocal * 256 + wr + m * 16 + (l >> 4) * 4 + j;
        if (lrow >= mcnt) continue;
        float v = acc[m][n][j] + bc;
        C[(long)lrow * F_DIM + col] = f2bf(gelu_exact(v));
      }
    }
  }
}

// ---------------------------------------------------------------- grouped GEMM2
// Flat grid. 128x128, BK=32, 4 waves, 2-phase. C=(A@B^T+bias)[*rowscale] f32.
// K=4096, N=1024, NB=8.
__global__ __launch_bounds__(256)
void moe_gemm2(const unsigned short* __restrict__ hbuf,
               const unsigned short* __restrict__ Wsh, const unsigned short* __restrict__ Wrt,
               const float* __restrict__ bsh, const float* __restrict__ brt,
               float* __restrict__ out, float* __restrict__ rout,
               const float* __restrict__ bwgt,
               const int* __restrict__ cnts, const int* __restrict__ offs,
               const int* __restrict__ tt) {
  __shared__ __align__(16) unsigned short lds[2][2][128][32];   // 32 KB
  const int wid = xcd_swizzle(blockIdx.x, G2_GRID);
  const int mt = wid >> 3, nb = wid & 7;
  if (mt >= tt[9]) return;
  int z = 0;
  while (mt >= tt[z + 1]) ++z;
  const int mlocal = mt - tt[z];

  const unsigned short* A;
  const unsigned short* Bp;
  const float* bias;
  float* C;
  const float* rs = nullptr;
  int mcnt;
  if (z == NEXP) {
    A = hbuf; Bp = Wsh; bias = bsh; C = out; mcnt = T_TOK;
  } else {
    const int off = offs[z];
    mcnt = cnts[z];
    A = hbuf + ((long)T_TOK + off) * F_DIM;
    Bp = Wrt + (long)z * H_DIM * F_DIM;
    bias = brt + z * H_DIM;
    C = rout + (long)off * H_DIM;
    rs = bwgt + off;
  }

  const int t = threadIdx.x;
  f32x4 acc[4][4] = {};
  const int nk = F_DIM >> 5;   // 128 K-steps

  auto stage = [&](int kt, int buf) {
    #pragma unroll
    for (int i = 0; i < 2; ++i) {
      const int row = i * 64 + (t >> 2);
      const int ch = (t & 3) * 8;
      const unsigned short* ga = A + (long)(mlocal * 128 + row) * F_DIM + kt * 32 + ch;
      const unsigned short* gb = Bp + (long)(nb * 128 + row) * F_DIM + kt * 32 + ch;
      unsigned short* la = &lds[buf][0][0][0] + i * 2048 + t * 8;
      unsigned short* lb = &lds[buf][1][0][0] + i * 2048 + t * 8;
      __builtin_amdgcn_global_load_lds((const __attribute__((address_space(1))) unsigned int*)ga,
                                       (__attribute__((address_space(3))) unsigned int*)la, 16, 0, 0);
      __builtin_amdgcn_global_load_lds((const __attribute__((address_space(1))) unsigned int*)gb,
                                       (__attribute__((address_space(3))) unsigned int*)lb, 16, 0, 0);
    }
  };

  const int l = t & 63;
  const int w = t >> 6;
  const int wr = (w >> 1) * 64, wc = (w & 1) * 64;
  const int lr = l & 15, lk = (l >> 4) * 8;

  auto compute = [&](int buf) {
    bf16x8 a[4], b[4];
    #pragma unroll
    for (int m = 0; m < 4; ++m) a[m] = *(const bf16x8*)&lds[buf][0][wr + m * 16 + lr][lk];
    #pragma unroll
    for (int n = 0; n < 4; ++n) b[n] = *(const bf16x8*)&lds[buf][1][wc + n * 16 + lr][lk];
    #pragma unroll
    for (int m = 0; m < 4; ++m)
      #pragma unroll
      for (int n = 0; n < 4; ++n)
        acc[m][n] = __builtin_amdgcn_mfma_f32_16x16x32_bf16(a[m], b[n], acc[m][n], 0, 0, 0);
  };

  stage(0, 0);
  asm volatile("s_waitcnt vmcnt(0)" ::: "memory");
  __syncthreads();
  for (int kt = 0; kt < nk - 1; ++kt) {
    const int cur = kt & 1;
    stage(kt + 1, cur ^ 1);
    compute(cur);
    asm volatile("s_waitcnt vmcnt(0)" ::: "memory");
    __syncthreads();
  }
  compute((nk - 1) & 1);

  const bool has_rs = (z != NEXP);
  #pragma unroll
  for (int m = 0; m < 4; ++m) {
    #pragma unroll
    for (int n = 0; n < 4; ++n) {
      const int col = nb * 128 + wc + n * 16 + lr;
      const float bc = bias[col];
      #pragma unroll
      for (int j = 0; j < 4; ++j) {
        const int lrow = mlocal * 128 + wr + m * 16 + (l >> 4) * 4 + j;
        if (lrow >= mcnt) continue;
        float v = acc[m][n][j] + bc;
        if (has_rs) v *= rs[lrow];
        C[(long)lrow * H_DIM + col] = v;
      }
    }
  }
}

// ---------------------------------------------------------------- host

extern "C" void kernel_launch(void* const* d_in, const int* in_sizes, int n_in,
                              void* d_out, int out_size, void* d_ws, size_t ws_size,
                              hipStream_t stream) {
  const float* x   = (const float*)d_in[0];
  const float* gw  = (const float*)d_in[1];
  const float* gb  = (const float*)d_in[2];
  const float* rb  = (const float*)d_in[3];
  const float* sw1 = (const float*)d_in[4];
  const float* sb1 = (const float*)d_in[5];
  const float* sw2 = (const float*)d_in[6];
  const float* sb2 = (const float*)d_in[7];
  const float* ew1 = (const float*)d_in[8];
  const float* eb1 = (const float*)d_in[9];
  const float* ew2 = (const float*)d_in[10];
  const float* eb2 = (const float*)d_in[11];

  char* wsp = (char*)d_ws;
  size_t o = 0;
  auto alloc = [&](size_t b) -> void* {
    void* p = wsp + o;
    o = (o + b + 255) & ~(size_t)255;
    return p;
  };
  unsigned short* x_bf = (unsigned short*)alloc((size_t)T_TOK * H_DIM * 2);
  // w1s|w2s|w1e|w2e contiguous (convert4 writes one flat dst)
  unsigned short* w1s  = (unsigned short*)alloc((size_t)F_DIM * H_DIM * 2);
  unsigned short* w2s  = (unsigned short*)alloc((size_t)H_DIM * F_DIM * 2);
  unsigned short* w1e  = (unsigned short*)alloc((size_t)NEXP * F_DIM * H_DIM * 2);
  unsigned short* w2e  = (unsigned short*)alloc((size_t)NEXP * H_DIM * F_DIM * 2);
  unsigned short* gx   = (unsigned short*)alloc((size_t)(RT + RPAD) * H_DIM * 2);
  unsigned short* hbuf = (unsigned short*)alloc((size_t)(T_TOK + RT + RPAD) * F_DIM * 2);
  float* rout          = (float*)alloc((size_t)RT * H_DIM * 4);
  int*   tok_e  = (int*)alloc(2 * T_TOK * 4);
  float* tok_w  = (float*)alloc(2 * T_TOK * 4);
  int*   tokpos = (int*)alloc(2 * T_TOK * 4);
  int*   btok   = (int*)alloc(RT * 4);
  float* bw     = (float*)alloc(RT * 4);
  int*   meta   = (int*)alloc(1024);
  int* counts = meta, *cursor = meta + 8, *offs = meta + 16;
  int* t1off = meta + 32, *t2off = meta + 48;
  (void)ws_size; (void)in_sizes; (void)n_in; (void)out_size;

  float* out = (float*)d_out;

  zero_kernel<<<1, 64, 0, stream>>>(meta);
  convert4_kernel<<<4096, 256, 0, stream>>>(sw1, sw2, ew1, ew2, w1s);
  gate_kernel<<<T_TOK, 64, 0, stream>>>(x, gw, gb, rb, x_bf, tok_e, tok_w, counts);
  scan_kernel<<<1, 1, 0, stream>>>(counts, offs, t1off, t2off);
  build_kernel<<<T_TOK / 256, 256, 0, stream>>>(tok_e, tok_w, offs, cursor, btok, bw, tokpos);
  gather_kernel<<<RT, 128, 0, stream>>>(x, btok, gx);

  // GEMM1: K=1024, N=4096; flat balanced grid.
  moe_gemm1<<<G1_GRID, 512, 0, stream>>>(
      x_bf, gx, w1s, w1e, sb1, eb1,
      hbuf, hbuf + (size_t)T_TOK * F_DIM, counts, offs, t1off);

  // GEMM2: K=4096, N=1024; flat balanced grid.
  moe_gemm2<<<G2_GRID, 256, 0, stream>>>(
      hbuf, w2s, w2e, sb2, eb2, out, rout, bw, counts, offs, t2off);

  combine_kernel<<<T_TOK, 256, 0, stream>>>(out, rout, tokpos);
}